// Round 3
// baseline (120.763 us; speedup 1.0000x reference)
//
#include <hip/hip_runtime.h>

#define ALPHA1 1.2566f
#define ALPHA2 1.5f
#define ALPHA3 0.9f
#define S_STAR 20.0f
#define TAU    4.0f

constexpr int TPB = 256;
constexpr int JPT = 4;             // j's per thread
constexpr int JPB = TPB * JPT;     // 1024 j's per block

// Single fused kernel.
//  Phase 0: issue row-slab (24KB) + column-view loads early (latency hides
//           under the fold).
//  Phase 1: wave-parallel fold of the purely-linear MLP:
//           wave m computes M[m][:] = sum_{i,h} W3[m,i] W2[i,h] W1[h,:]
//           and c[m], via coalesced W2 loads + 64-lane shuffle reduce.
//  Phase 2: barrier math, 4 j's per thread, all loads coalesced, no divides.
__global__ __launch_bounds__(TPB) void fused_kernel(
        const float* __restrict__ z,
        const float* __restrict__ W1, const float* __restrict__ b1,
        const float* __restrict__ W2, const float* __restrict__ b2,
        const float* __restrict__ W3, const float* __restrict__ b3,
        float* __restrict__ out, long long B) {
    __shared__ float w1s[300];
    __shared__ float b1s[50];
    __shared__ float b2s[100];
    __shared__ float Ms[4][6];
    __shared__ float cs[4];
    __shared__ float slab[JPB * 6];   // 24 KB row-view slab

    const int tid = threadIdx.x;
    const long long blockBase = (long long)blockIdx.x * JPB;

    // ---- issue the big streaming loads EARLY (fill the pipe) ----
    float4 s4[6];
    const float4* zr4 = (const float4*)(z + blockBase * 6);
    #pragma unroll
    for (int it = 0; it < 6; ++it) s4[it] = zr4[it * TPB + tid];

    const long long j0 = blockBase + (long long)tid * JPT;
    float4 col[6];
    #pragma unroll
    for (int i = 0; i < 6; ++i)
        col[i] = *(const float4*)(z + (long long)i * B + j0);

    // ---- stage fold inputs to LDS ----
    for (int idx = tid; idx < 300; idx += TPB) w1s[idx] = W1[idx];
    if (tid < 50) b1s[tid] = b1[tid];
    else if (tid >= 64 && tid < 164) b2s[tid - 64] = b2[tid - 64];
    __syncthreads();

    // ---- wave-parallel fold: wave m -> M[m][:], c[m] ----
    {
        const int m    = tid >> 6;    // wave id 0..3
        const int lane = tid & 63;
        float acc[8] = {0.f, 0.f, 0.f, 0.f, 0.f, 0.f, 0.f, 0.f};
        for (int p = lane; p < 5000; p += 64) {
            const int i = p / 50;
            const int h = p - i * 50;
            const float w3 = W3[m * 100 + i];
            const float t  = w3 * W2[p];          // W2 coalesced: addr == p
            acc[6] = fmaf(t, b1s[h], acc[6]);
            #pragma unroll
            for (int k = 0; k < 6; ++k)
                acc[k] = fmaf(t, w1s[h * 6 + k], acc[k]);
            if (h == 0) acc[7] = fmaf(w3, b2s[i], acc[7]);
        }
        #pragma unroll
        for (int off = 32; off > 0; off >>= 1) {
            #pragma unroll
            for (int r = 0; r < 8; ++r) acc[r] += __shfl_xor(acc[r], off);
        }
        if (lane == 0) {
            #pragma unroll
            for (int k = 0; k < 6; ++k) Ms[m][k] = acc[k];
            cs[m] = b3[m] + acc[6] + acc[7];
        }
    }

    // ---- write row slab to LDS ----
    #pragma unroll
    for (int it = 0; it < 6; ++it)
        *(float4*)(&slab[(it * TPB + tid) * 4]) = s4[it];
    __syncthreads();

    float M[4][6], c[4];
    #pragma unroll
    for (int m = 0; m < 4; ++m) {
        #pragma unroll
        for (int k = 0; k < 6; ++k) M[m][k] = Ms[m][k];
        c[m] = cs[m];
    }

    // d3u = d3 @ f (compile-time constants)
    const float g1 = TAU * ALPHA3;
    const float g2 = TAU * ALPHA1;
    const float g3 = 1.f - TAU * ALPHA2 - TAU * ALPHA3;
    const float g4 = -TAU * ALPHA1;
    const float g5 = TAU * ALPHA2 - 1.f;
    const float invA1 = -0.25f;               // 1/(-TAU), exact
    const float invA2 = -1.f / (TAU * ALPHA3);

    // row view out of LDS (thread t owns slab[24t .. 24t+23])
    float zz[24];
    #pragma unroll
    for (int v = 0; v < 6; ++v) {
        const float4 q = *(const float4*)(&slab[tid * 24 + v * 4]);
        zz[4 * v + 0] = q.x; zz[4 * v + 1] = q.y;
        zz[4 * v + 2] = q.z; zz[4 * v + 3] = q.w;
    }

    float4 o;
    float* op = &o.x;
    const float* cp[6] = {&col[0].x, &col[1].x, &col[2].x,
                          &col[3].x, &col[4].x, &col[5].x};
    #pragma unroll
    for (int r = 0; r < 4; ++r) {
        float u[4];
        #pragma unroll
        for (int m = 0; m < 4; ++m) {
            float s = c[m];
            #pragma unroll
            for (int k = 0; k < 6; ++k) s = fmaf(M[m][k], zz[r * 6 + k], s);
            u[m] = s;
        }
        const float x1 = cp[1][r], x2 = cp[2][r], x3 = cp[3][r];
        const float x4 = cp[4][r], x5 = cp[5][r];

        const float fx2 = x1 - x3;
        const float fx3 = ALPHA3 * x1 + ALPHA1 * x2 - ALPHA2 * x3;
        const float fx4 = x3 - x5;
        const float fx5 = ALPHA3 * x3 + ALPHA1 * x4 - ALPHA2 * x5;

        const float eta1 = x2 + S_STAR - TAU * (x3 - x1);
        const float bb1  = (fx2 - TAU * fx3) + u[1] * eta1;

        const float eta2a = x4 + S_STAR - TAU * (x5 - x3);
        const float eta2b = g1 * x1 + g2 * x2 + g3 * x3 + g4 * x4 + g5 * x5;
        const float d3ufX = g2 * fx2 + g3 * fx3 + g4 * fx4 + g5 * fx5;
        const float bb2   = d3ufX + u[2] * eta2a + u[3] * eta2b;

        const float lb = fmaxf(bb1 * invA1, bb2 * invA2);
        const float xu = 2.f * u[0];
        op[r] = fminf(fmaxf(xu, lb), 1e30f);
    }
    *(float4*)(out + j0) = o;
}

extern "C" void kernel_launch(void* const* d_in, const int* in_sizes, int n_in,
                              void* d_out, int out_size, void* d_ws, size_t ws_size,
                              hipStream_t stream) {
    const float* z  = (const float*)d_in[0];
    // d_in[1] = tilde_vh (unused by the reference output)
    const float* W1 = (const float*)d_in[2];
    const float* b1 = (const float*)d_in[3];
    const float* W2 = (const float*)d_in[4];
    const float* b2 = (const float*)d_in[5];
    const float* W3 = (const float*)d_in[6];
    const float* b3 = (const float*)d_in[7];
    float* out = (float*)d_out;

    const long long B = (long long)in_sizes[0] / 6;   // 1048576
    const int blocks = (int)(B / JPB);                // 1024

    fused_kernel<<<blocks, TPB, 0, stream>>>(z, W1, b1, W2, b2, W3, b3, out, B);
}

// Round 4
// 92.450 us; speedup vs baseline: 1.3063x; 1.3063x over previous
//
#include <hip/hip_runtime.h>

#define ALPHA1 1.2566f
#define ALPHA2 1.5f
#define ALPHA3 0.9f
#define S_STAR 20.0f
#define TAU    4.0f

constexpr int TPB = 256;
constexpr int JPT = 2;             // j's per thread
constexpr int JPB = TPB * JPT;     // 512 j's per block

// Single fused kernel, fold made VMEM-cheap and kept off the critical path.
//   early:  issue all streaming loads (row view 3xfloat4, col view 5xfloat2)
//   fold A: T[i][k] = sum_h W2[i,h]*W1[h,k]   (k=6 col carries b2 + W2*b1)
//           100 threads, vectorized float2 W2-row loads, W1|b1 from LDS
//   fold B: Mc[m][k] = sum_i W3[m,i]*T[i][k]  (k=6 col carries c[m])
//           28 threads
//   math:   barrier computation, 2 j's per thread, no divides; M,c read as
//           LDS broadcasts to keep VGPR <= 64 (8 blocks/CU).
__global__ __launch_bounds__(TPB, 8) void fused_kernel(
        const float* __restrict__ z,
        const float* __restrict__ W1, const float* __restrict__ b1,
        const float* __restrict__ W2, const float* __restrict__ b2,
        const float* __restrict__ W3, const float* __restrict__ b3,
        float* __restrict__ out, long long B) {
    __shared__ float W1e[50][8];   // [h][0..5]=W1 row h, [6]=b1[h]
    __shared__ float T[100][8];    // [i][0..5]=(W2@W1)[i,:], [6]=b2[i]+(W2@b1)[i]
    __shared__ float Mc[4][8];     // [m][0..5]=M row m,     [6]=c[m]

    const int tid = threadIdx.x;
    const long long j0 = ((long long)blockIdx.x * TPB + tid) * JPT;

    // ---- issue streaming loads early; latency hides under the fold ----
    const float4 r0 = *(const float4*)(z + j0 * 6);
    const float4 r1 = *(const float4*)(z + j0 * 6 + 4);
    const float4 r2 = *(const float4*)(z + j0 * 6 + 8);
    const float2 c1 = *(const float2*)(z + 1 * B + j0);
    const float2 c2 = *(const float2*)(z + 2 * B + j0);
    const float2 c3 = *(const float2*)(z + 3 * B + j0);
    const float2 c4 = *(const float2*)(z + 4 * B + j0);
    const float2 c5 = *(const float2*)(z + 5 * B + j0);

    // ---- stage W1|b1 ----
    if (tid < 50) {
        const float2 a = *(const float2*)(W1 + tid * 6);
        const float2 b = *(const float2*)(W1 + tid * 6 + 2);
        const float2 d = *(const float2*)(W1 + tid * 6 + 4);
        W1e[tid][0] = a.x; W1e[tid][1] = a.y;
        W1e[tid][2] = b.x; W1e[tid][3] = b.y;
        W1e[tid][4] = d.x; W1e[tid][5] = d.y;
        W1e[tid][6] = b1[tid];
    }
    __syncthreads();

    // ---- fold A: rows of T = W2 @ [W1 | b1] (+ b2 in col 6) ----
    if (tid < 100) {
        float acc[7] = {0.f, 0.f, 0.f, 0.f, 0.f, 0.f, 0.f};
        acc[6] = b2[tid];
        const float2* wrow = (const float2*)(W2 + tid * 50);
        #pragma unroll 5
        for (int hh = 0; hh < 25; ++hh) {
            const float2 w = wrow[hh];
            const int h = 2 * hh;
            #pragma unroll
            for (int k = 0; k < 7; ++k)
                acc[k] = fmaf(w.y, W1e[h + 1][k], fmaf(w.x, W1e[h][k], acc[k]));
        }
        #pragma unroll
        for (int k = 0; k < 7; ++k) T[tid][k] = acc[k];
    }
    __syncthreads();

    // ---- fold B: Mc = W3 @ T (+ b3 in col 6) ----
    if (tid < 28) {
        const int m = tid / 7, k = tid % 7;
        float s = (k == 6) ? b3[m] : 0.f;
        #pragma unroll 10
        for (int i = 0; i < 100; ++i)
            s = fmaf(W3[m * 100 + i], T[i][k], s);
        Mc[m][k] = s;
    }
    __syncthreads();

    // d3u = d3 @ f (compile-time constants)
    const float g1 = TAU * ALPHA3;
    const float g2 = TAU * ALPHA1;
    const float g3 = 1.f - TAU * ALPHA2 - TAU * ALPHA3;
    const float g4 = -TAU * ALPHA1;
    const float g5 = TAU * ALPHA2 - 1.f;
    const float invA1 = -0.25f;                 // 1/(-TAU), exact
    const float invA2 = -1.f / (TAU * ALPHA3);

    const float zz[12] = {r0.x, r0.y, r0.z, r0.w,
                          r1.x, r1.y, r1.z, r1.w,
                          r2.x, r2.y, r2.z, r2.w};

    float2 o;
    float* op = &o.x;
    #pragma unroll
    for (int r = 0; r < 2; ++r) {
        float u[4];
        #pragma unroll
        for (int m = 0; m < 4; ++m) {
            float s = Mc[m][6];                 // LDS broadcast
            #pragma unroll
            for (int k = 0; k < 6; ++k)
                s = fmaf(Mc[m][k], zz[r * 6 + k], s);
            u[m] = s;
        }
        const float x1 = r ? c1.y : c1.x;
        const float x2 = r ? c2.y : c2.x;
        const float x3 = r ? c3.y : c3.x;
        const float x4 = r ? c4.y : c4.x;
        const float x5 = r ? c5.y : c5.x;

        const float fx2 = x1 - x3;
        const float fx3 = ALPHA3 * x1 + ALPHA1 * x2 - ALPHA2 * x3;
        const float fx4 = x3 - x5;
        const float fx5 = ALPHA3 * x3 + ALPHA1 * x4 - ALPHA2 * x5;

        const float eta1 = x2 + S_STAR - TAU * (x3 - x1);
        const float bb1  = (fx2 - TAU * fx3) + u[1] * eta1;

        const float eta2a = x4 + S_STAR - TAU * (x5 - x3);
        const float eta2b = g1 * x1 + g2 * x2 + g3 * x3 + g4 * x4 + g5 * x5;
        const float d3ufX = g2 * fx2 + g3 * fx3 + g4 * fx4 + g5 * fx5;
        const float bb2   = d3ufX + u[2] * eta2a + u[3] * eta2b;

        const float lb = fmaxf(bb1 * invA1, bb2 * invA2);
        const float xu = 2.f * u[0];
        op[r] = fminf(fmaxf(xu, lb), 1e30f);
    }
    *(float2*)(out + j0) = o;
}

extern "C" void kernel_launch(void* const* d_in, const int* in_sizes, int n_in,
                              void* d_out, int out_size, void* d_ws, size_t ws_size,
                              hipStream_t stream) {
    const float* z  = (const float*)d_in[0];
    // d_in[1] = tilde_vh (unused by the reference output)
    const float* W1 = (const float*)d_in[2];
    const float* b1 = (const float*)d_in[3];
    const float* W2 = (const float*)d_in[4];
    const float* b2 = (const float*)d_in[5];
    const float* W3 = (const float*)d_in[6];
    const float* b3 = (const float*)d_in[7];
    float* out = (float*)d_out;

    const long long B = (long long)in_sizes[0] / 6;   // 1048576
    const int blocks = (int)(B / JPB);                // 2048

    fused_kernel<<<blocks, TPB, 0, stream>>>(z, W1, b1, W2, b2, W3, b3, out, B);
}